// Round 4
// baseline (293.544 us; speedup 1.0000x reference)
//
#include <hip/hip_runtime.h>
#include <cstdint>
#include <cstddef>

#define BN_EPSF 1e-5f

constexpr int B_  = 32, N_ = 512, F_ = 1024, E_ = 32768;
constexpr int H1_ = 512, H2_ = 256, H3_ = 128, NC_ = 8, EC_ = 10;
constexpr int M_  = B_ * N_;      // 16384 node rows
constexpr int NE_ = B_ * E_;      // 1048576 edges

typedef short bf16x8 __attribute__((ext_vector_type(8)));
typedef float f32x4  __attribute__((ext_vector_type(4)));

__device__ __forceinline__ short f2bf(float f) {
  union { float f; unsigned u; } v; v.f = f;
  unsigned r = v.u + 0x7fffu + ((v.u >> 16) & 1u);   // RNE
  return (short)(r >> 16);
}
__device__ __forceinline__ float bfbits(unsigned u) {
  union { unsigned u; float f; } v; v.u = u; return v.f;
}
// RNE-round two floats to bf16 and pack into one u32 (a -> low, b -> high)
__device__ __forceinline__ unsigned rnepack(float a, float b) {
  unsigned ua = __float_as_uint(a); ua = ua + 0x7fffu + ((ua >> 16) & 1u);
  unsigned ub = __float_as_uint(b); ub = ub + 0x7fffu + ((ub >> 16) & 1u);
  return __builtin_amdgcn_perm(ub, ua, 0x07060302u);  // [ua.hi16 | ub.hi16]
}

// ---------------------------------------------------------------------------
// fused prep: roi fp32->bf16 | 3x weight transpose+convert | node-attr bf16
// ---------------------------------------------------------------------------
__device__ __forceinline__ void wt_body(
    const float* __restrict__ W, short* __restrict__ Wt, int K, int N,
    int bx, int by, float (*s)[33])
{
  const int tx = threadIdx.x & 31, ty = threadIdx.x >> 5;
  const int k0 = by * 32, n0 = bx * 32;
#pragma unroll
  for (int r = 0; r < 4; r++)
    s[ty * 4 + r][tx] = W[(size_t)(k0 + ty * 4 + r) * N + n0 + tx];
  __syncthreads();
#pragma unroll
  for (int r = 0; r < 4; r++)
    Wt[(size_t)(n0 + ty * 4 + r) * K + k0 + tx] = f2bf(s[tx][ty * 4 + r]);
}

__global__ __launch_bounds__(256) void k_prep(
    const float* __restrict__ roi, ushort* __restrict__ roiB,
    const float* __restrict__ w1, short* __restrict__ w1t,
    const float* __restrict__ w2, short* __restrict__ w2t,
    const float* __restrict__ w3, short* __restrict__ w3t,
    const float* __restrict__ bbox, const float* __restrict__ dir,
    const float* __restrict__ pri, ushort* __restrict__ nab)
{
  __shared__ float s[32][33];
  const int bx = blockIdx.x;
  if (bx < 8192) {                       // roi -> bf16, 8 elems/thread
    int i = bx * 256 + threadIdx.x;
    float4 a = *(const float4*)(roi + (size_t)i * 8);
    float4 b = *(const float4*)(roi + (size_t)i * 8 + 4);
    unsigned o[4];
    o[0] = rnepack(a.x, a.y); o[1] = rnepack(a.z, a.w);
    o[2] = rnepack(b.x, b.y); o[3] = rnepack(b.z, b.w);
    *(uint4*)(roiB + (size_t)i * 8) = *(uint4*)o;
  } else if (bx < 8704) {                // w1t: K=1024 N=512
    int idx = bx - 8192; wt_body(w1, w1t, F_, H1_, idx & 15, idx >> 4, s);
  } else if (bx < 8832) {                // w2t: K=512 N=256
    int idx = bx - 8704; wt_body(w2, w2t, H1_, H2_, idx & 7, idx >> 3, s);
  } else if (bx < 8864) {                // w3t: K=256 N=128
    int idx = bx - 8832; wt_body(w3, w3t, H2_, H3_, idx & 3, idx >> 2, s);
  } else {                               // node attrs -> bf16, stride 16
    int i = (bx - 8864) * 256 + threadIdx.x;
    float4 b = *(const float4*)(bbox + (size_t)i * 4);
    float4 d = *(const float4*)(dir + (size_t)i * 4);
    float p = pri[i];
    const float inv = 1.0f / 1024.0f;
    unsigned o[8];
    o[0] = rnepack(b.x * inv, b.y * inv);
    o[1] = rnepack(b.z * inv, b.w * inv);
    o[2] = rnepack(d.x, d.y); o[3] = rnepack(d.z, d.w);
    o[4] = rnepack(p, 0.f);   o[5] = 0; o[6] = 0; o[7] = 0;
    *(uint4*)(nab + (size_t)i * 16) = *(uint4*)&o[0];
    *(uint4*)(nab + (size_t)i * 16 + 8) = *(uint4*)&o[4];
  }
}

// ---------------------------------------------------------------------------
// bf16 MFMA GEMM (m97 structure): C = epi(A@B + bias)
// ---------------------------------------------------------------------------
template <int EPI>
__global__ __launch_bounds__(256) void k_gemm_mfma(
    const short* __restrict__ A, const short* __restrict__ Wt,
    const float* __restrict__ bias,
    const float* __restrict__ g, const float* __restrict__ bb,
    const float* __restrict__ rm, const float* __restrict__ rv,
    short* __restrict__ C, int M, int K, int N)
{
  __shared__ short As[128 * 32];
  __shared__ short Bs[128 * 32];

  const int tid  = threadIdx.x;
  const int wave = tid >> 6, lane = tid & 63;
  const int m0 = blockIdx.y * 128, n0 = blockIdx.x * 128;
  const int wm = wave >> 1, wn = wave & 1;

  const int arow = tid >> 2;
  const int akq  = (tid & 3) * 8;

  f32x4 acc[4][4] = {};

  for (int k0 = 0; k0 < K; k0 += 32) {
#pragma unroll
    for (int it = 0; it < 2; it++) {
      const short* gp = A + (size_t)(m0 + it * 64 + arow) * K + k0 + akq;
      char* lp = (char*)As + it * 4096 + wave * 1024;
      __builtin_amdgcn_global_load_lds(
          (const __attribute__((address_space(1))) void*)gp,
          (__attribute__((address_space(3))) void*)lp, 16, 0, 0);
    }
#pragma unroll
    for (int it = 0; it < 2; it++) {
      const short* gp = Wt + (size_t)(n0 + it * 64 + arow) * K + k0 + akq;
      char* lp = (char*)Bs + it * 4096 + wave * 1024;
      __builtin_amdgcn_global_load_lds(
          (const __attribute__((address_space(1))) void*)gp,
          (__attribute__((address_space(3))) void*)lp, 16, 0, 0);
    }
    __syncthreads();

    const int ko = (lane >> 4) * 8;
    bf16x8 af[4], bfr[4];
#pragma unroll
    for (int t = 0; t < 4; t++) {
      af[t]  = *(const bf16x8*)&As[(wm * 64 + t * 16 + (lane & 15)) * 32 + ko];
      bfr[t] = *(const bf16x8*)&Bs[(wn * 64 + t * 16 + (lane & 15)) * 32 + ko];
    }
#pragma unroll
    for (int ti = 0; ti < 4; ti++)
#pragma unroll
      for (int tj = 0; tj < 4; tj++)
        acc[ti][tj] = __builtin_amdgcn_mfma_f32_16x16x32_bf16(
            af[ti], bfr[tj], acc[ti][tj], 0, 0, 0);
    __syncthreads();
  }

#pragma unroll
  for (int tj = 0; tj < 4; tj++) {
    const int col = n0 + wn * 64 + tj * 16 + (lane & 15);
    const float bi = bias[col];
    float s = 1.f, t = 0.f;
    if (EPI == 0) {
      s = g[col] * rsqrtf(rv[col] + BN_EPSF);
      t = bb[col] - rm[col] * s;
    }
#pragma unroll
    for (int ti = 0; ti < 4; ti++) {
      const int rbase = m0 + wm * 64 + ti * 16 + ((lane >> 4) << 2);
#pragma unroll
      for (int r = 0; r < 4; r++) {
        float v = acc[ti][tj][r] + bi;
        if (EPI == 0) v = fmaf(v, s, t);
        v = fmaxf(v, 0.f);
        C[(size_t)(rbase + r) * N + col] = f2bf(v);
      }
    }
  }
}

// ---------------------------------------------------------------------------
// node head: sigmoid(h3 @ ni_w + ni_b), h3 bf16, K=128, N=8.
// ---------------------------------------------------------------------------
__global__ __launch_bounds__(256) void k_node_head(
    const ushort* __restrict__ h3, const float* __restrict__ w,
    const float* __restrict__ b, float* __restrict__ out)
{
  __shared__ __align__(16) float sw[H3_ * NC_];
  __shared__ float sb[NC_];
  for (int i = threadIdx.x; i < H3_ * NC_; i += 256) sw[i] = w[i];
  if (threadIdx.x < NC_) sb[threadIdx.x] = b[threadIdx.x];
  __syncthreads();

  int row = blockIdx.x * 256 + threadIdx.x;
  if (row >= M_) return;
  const ushort* hr = h3 + (size_t)row * H3_;
  float acc[NC_];
#pragma unroll
  for (int c = 0; c < NC_; c++) acc[c] = sb[c];
  for (int k = 0; k < H3_; k += 8) {
    uint4 u = *(const uint4*)&hr[k];
    float hv[8];
    hv[0] = bfbits(u.x << 16); hv[1] = bfbits(u.x & 0xffff0000u);
    hv[2] = bfbits(u.y << 16); hv[3] = bfbits(u.y & 0xffff0000u);
    hv[4] = bfbits(u.z << 16); hv[5] = bfbits(u.z & 0xffff0000u);
    hv[6] = bfbits(u.w << 16); hv[7] = bfbits(u.w & 0xffff0000u);
#pragma unroll
    for (int kk = 0; kk < 8; kk++)
#pragma unroll
      for (int c = 0; c < NC_; c++)
        acc[c] = fmaf(hv[kk], sw[(k + kk) * NC_ + c], acc[c]);
  }
  float4 o1, o2;
  float* p1 = (float*)&o1; float* p2 = (float*)&o2;
#pragma unroll
  for (int c = 0; c < 4; c++) {
    p1[c] = 1.f / (1.f + __expf(-acc[c]));
    p2[c] = 1.f / (1.f + __expf(-acc[c + 4]));
  }
  *(float4*)&out[(size_t)row * NC_ + 0] = o1;
  *(float4*)&out[(size_t)row * NC_ + 4] = o2;
}

// ---------------------------------------------------------------------------
// edge MLP v2: weights-as-A MFMA chain, inter-layer transform in REGISTERS.
// Validated operand convention (round 3): mfma(X, Y, acc) -> C[row=X's row]
// [col=Y's row], C-layout col=lane&15, row=quad*4+reg.
// Layer L computed as H[out][edge]; lane then holds col=edge(lane&15),
// rows=out-ch(quad*4+r) == exactly the next layer's B-frag after a quad
// permutation (ds_bpermute among lanes {lm, lm+16, lm+32, lm+48}).
// LDS only stages X (128 x 40 shorts); 2 barriers per 128-edge batch.
// ---------------------------------------------------------------------------
__global__ __launch_bounds__(256) void k_edge2(
    const ushort* __restrict__ nab, const int* __restrict__ eidx,
    const float* __restrict__ w1, const float* __restrict__ b1,
    const float* __restrict__ w2, const float* __restrict__ b2,
    const float* __restrict__ wo, const float* __restrict__ bo,
    float* __restrict__ out)
{
  __shared__ ushort sX[128 * 40];   // 10240 B, row stride 80 B (16B-aligned)

  const int tid  = threadIdx.x;
  const int wave = tid >> 6, lane = tid & 63;
  const int lm = lane & 15;
  const int q  = lane >> 4;

  // ---- weight A-fragments from global (L2-cached, once per block) ----
  bf16x8 fW1[4];                       // L1: A[m=ti*16+lm][k=q*8+j], K pad 18->32
#pragma unroll
  for (int ti = 0; ti < 4; ti++) {
    ushort tmp[8];
#pragma unroll
    for (int j = 0; j < 8; j++) {
      int k = q * 8 + j;
      tmp[j] = (k < 18) ? (ushort)f2bf(w1[k * 64 + ti * 16 + lm]) : (ushort)0;
    }
    fW1[ti] = *(bf16x8*)tmp;
  }
  bf16x8 fW2[4][2];                    // L2: K=64, 2 chunks of 32
#pragma unroll
  for (int ti = 0; ti < 4; ti++)
#pragma unroll
    for (int ks = 0; ks < 2; ks++) {
      ushort tmp[8];
#pragma unroll
      for (int j = 0; j < 8; j++)
        tmp[j] = (ushort)f2bf(w2[(ks * 32 + q * 8 + j) * 64 + ti * 16 + lm]);
      fW2[ti][ks] = *(bf16x8*)tmp;
    }
  bf16x8 fW3[2];                       // L3: out 16 (10 real), K=64
#pragma unroll
  for (int ks = 0; ks < 2; ks++) {
    ushort tmp[8];
#pragma unroll
    for (int j = 0; j < 8; j++)
      tmp[j] = (lm < 10) ? (ushort)f2bf(wo[(ks * 32 + q * 8 + j) * 10 + lm])
                         : (ushort)0;
    fW3[ks] = *(bf16x8*)tmp;
  }
  f32x4 b1v[4], b2v[4], bov;
#pragma unroll
  for (int ti = 0; ti < 4; ti++)
#pragma unroll
    for (int r = 0; r < 4; r++) {
      b1v[ti][r] = b1[ti * 16 + q * 4 + r];
      b2v[ti][r] = b2[ti * 16 + q * 4 + r];
    }
#pragma unroll
  for (int r = 0; r < 4; r++)
    bov[r] = (q * 4 + r < 10) ? bo[q * 4 + r] : 0.f;

  // bpermute lane addresses (bytes): source quads 2*(q&1) and 2*(q&1)+1
  const int srcA = ((q & 1) * 32 + lm) * 4;
  const int srcB = srcA + 64;
  const bool qhi = (q >> 1) != 0;      // selects odd ti_src

  // zero sX once (k-pad region 18..31 must read as 0 forever)
  for (int i = tid; i < 128 * 40 / 2; i += 256) ((unsigned*)sX)[i] = 0;
  __syncthreads();

  const int eblk = blockIdx.x * 1024;
  for (int bi = 0; bi < 8; bi++) {
    const int e0 = eblk + bi * 128;

    // ---- gather 128 edges -> X rows (bf16, shorts 0..17; 18..31 stay 0) ----
    if (tid < 128) {
      int e = e0 + tid;
      int b = e >> 15, kk = e & (E_ - 1);
      const int* ei = eidx + (size_t)b * 2 * E_;
      int s = ei[kk], d = ei[E_ + kk];
      const ushort* ps = nab + (size_t)(b * N_ + s) * 16;
      const ushort* pd = nab + (size_t)(b * N_ + d) * 16;
      uint4 x0 = *(const uint4*)ps;                 // src attrs 0..7
      unsigned x1 = *(const unsigned*)(ps + 8);     // src attr 8 in lo16
      uint4 y0 = *(const uint4*)pd;                 // dst attrs 0..7
      unsigned y1 = *(const unsigned*)(pd + 8);     // dst attr 8 in lo16
      uint4 m;
      m.x = (x1 & 0xffffu) | (y0.x << 16);          // (s8, d0)
      m.y = (y0.x >> 16)   | (y0.y << 16);          // (d1, d2)
      m.z = (y0.y >> 16)   | (y0.z << 16);          // (d3, d4)
      m.w = (y0.z >> 16)   | (y0.w << 16);          // (d5, d6)
      unsigned p4 = (y0.w >> 16) | (y1 << 16);      // (d7, d8)
      unsigned* row = (unsigned*)&sX[tid * 40];
      *(uint4*)(row)     = x0;                      // shorts 0..7
      *(uint4*)(row + 4) = m;                       // shorts 8..15
      row[8] = p4;                                  // shorts 16..17
    }
    __syncthreads();

#pragma unroll
    for (int nt = 0; nt < 2; nt++) {
      const int ntile = wave * 2 + nt;
      const int eb = e0 + ntile * 16;

      bf16x8 xb = *(const bf16x8*)&sX[(ntile * 16 + lm) * 40 + q * 8];

      // ---- L1: H1[64][16] ----
      f32x4 a1[4];
#pragma unroll
      for (int ti = 0; ti < 4; ti++) {
        a1[ti] = b1v[ti];
        a1[ti] = __builtin_amdgcn_mfma_f32_16x16x32_bf16(fW1[ti], xb, a1[ti], 0, 0, 0);
      }
      unsigned h1p[4][2];
#pragma unroll
      for (int ti = 0; ti < 4; ti++) {
        h1p[ti][0] = rnepack(fmaxf(a1[ti][0], 0.f), fmaxf(a1[ti][1], 0.f));
        h1p[ti][1] = rnepack(fmaxf(a1[ti][2], 0.f), fmaxf(a1[ti][3], 0.f));
      }

      // ---- L2: H2[64][16], B-frag built by register quad-permute ----
      f32x4 a2[4];
#pragma unroll
      for (int ti = 0; ti < 4; ti++) a2[ti] = b2v[ti];
#pragma unroll
      for (int ks = 0; ks < 2; ks++) {
        unsigned s0 = qhi ? h1p[ks * 2 + 1][0] : h1p[ks * 2][0];
        unsigned s1 = qhi ? h1p[ks * 2 + 1][1] : h1p[ks * 2][1];
        unsigned f[4];
        f[0] = __builtin_amdgcn_ds_bpermute(srcA, (int)s0);
        f[1] = __builtin_amdgcn_ds_bpermute(srcA, (int)s1);
        f[2] = __builtin_amdgcn_ds_bpermute(srcB, (int)s0);
        f[3] = __builtin_amdgcn_ds_bpermute(srcB, (int)s1);
        bf16x8 bfrag = *(bf16x8*)f;
#pragma unroll
        for (int ti = 0; ti < 4; ti++)
          a2[ti] = __builtin_amdgcn_mfma_f32_16x16x32_bf16(fW2[ti][ks], bfrag, a2[ti], 0, 0, 0);
      }
      unsigned h2p[4][2];
#pragma unroll
      for (int ti = 0; ti < 4; ti++) {
        h2p[ti][0] = rnepack(fmaxf(a2[ti][0], 0.f), fmaxf(a2[ti][1], 0.f));
        h2p[ti][1] = rnepack(fmaxf(a2[ti][2], 0.f), fmaxf(a2[ti][3], 0.f));
      }

      // ---- L3: out[16(10)][16] ----
      f32x4 a3 = bov;
#pragma unroll
      for (int ks = 0; ks < 2; ks++) {
        unsigned s0 = qhi ? h2p[ks * 2 + 1][0] : h2p[ks * 2][0];
        unsigned s1 = qhi ? h2p[ks * 2 + 1][1] : h2p[ks * 2][1];
        unsigned f[4];
        f[0] = __builtin_amdgcn_ds_bpermute(srcA, (int)s0);
        f[1] = __builtin_amdgcn_ds_bpermute(srcA, (int)s1);
        f[2] = __builtin_amdgcn_ds_bpermute(srcB, (int)s0);
        f[3] = __builtin_amdgcn_ds_bpermute(srcB, (int)s1);
        bf16x8 bfrag = *(bf16x8*)f;
        a3 = __builtin_amdgcn_mfma_f32_16x16x32_bf16(fW3[ks], bfrag, a3, 0, 0, 0);
      }

      float* op = out + (size_t)(eb + lm) * 10;
#pragma unroll
      for (int r = 0; r < 4; r++) {
        int c = q * 4 + r;
        if (c < 10) op[c] = 1.f / (1.f + __expf(-a3[r]));
      }
    }
    __syncthreads();   // protect sX before next batch's gather
  }
}

// ---------------------------------------------------------------------------
extern "C" void kernel_launch(void* const* d_in, const int* in_sizes, int n_in,
                              void* d_out, int out_size, void* d_ws, size_t ws_size,
                              hipStream_t stream)
{
  const float* roi   = (const float*)d_in[0];
  const float* bbox  = (const float*)d_in[1];
  const float* dir   = (const float*)d_in[2];
  const float* pri   = (const float*)d_in[3];
  const int*   eidx  = (const int*)d_in[4];
  const float* w1    = (const float*)d_in[5];
  const float* b1    = (const float*)d_in[6];
  const float* g1    = (const float*)d_in[7];
  const float* bb1   = (const float*)d_in[8];
  const float* rm1   = (const float*)d_in[9];
  const float* rv1   = (const float*)d_in[10];
  const float* w2    = (const float*)d_in[11];
  const float* b2    = (const float*)d_in[12];
  const float* g2    = (const float*)d_in[13];
  const float* bb2   = (const float*)d_in[14];
  const float* rm2   = (const float*)d_in[15];
  const float* rv2   = (const float*)d_in[16];
  const float* w3    = (const float*)d_in[17];
  const float* b3    = (const float*)d_in[18];
  const float* niw   = (const float*)d_in[19];
  const float* nib   = (const float*)d_in[20];
  const float* ew1   = (const float*)d_in[21];
  const float* eb1   = (const float*)d_in[22];
  const float* ew2   = (const float*)d_in[23];
  const float* eb2   = (const float*)d_in[24];
  const float* eow   = (const float*)d_in[25];
  const float* eob   = (const float*)d_in[26];

  float* out_node = (float*)d_out;                    // 16384 x 8
  float* out_edge = (float*)d_out + (size_t)M_ * NC_; // 1048576 x 10

  // workspace layout (bytes); h2/h3 overlay roiB (dead after L1 GEMM)
  char* w = (char*)d_ws;
  short*  roiB = (short*)w;                                   // 33,554,432
  short*  h2   = (short*)w;                                   // 8,388,608
  ushort* h3   = (ushort*)(w + 8388608);                      // 4,194,304
  short*  h1   = (short*)(w + 33554432);                      // 16,777,216
  short*  w1t  = (short*)(w + 33554432 + 16777216);           // 1,048,576
  short*  w2t  = (short*)(w + 33554432 + 16777216 + 1048576); //   262,144
  short*  w3t  = (short*)(w + 33554432 + 16777216 + 1310720); //    65,536
  ushort* nab  = (ushort*)(w + 33554432 + 16777216 + 1376256);//   524,288

  // fused conversions + node-attr pack (1 launch)
  k_prep<<<8928, 256, 0, stream>>>(roi, (ushort*)roiB, w1, w1t, w2, w2t,
                                   w3, w3t, bbox, dir, pri, nab);

  // edge MLP (register-chained MFMA)
  k_edge2<<<NE_ / 1024, 256, 0, stream>>>(nab, eidx, ew1, eb1, ew2, eb2,
                                          eow, eob, out_edge);

  // node MLP (bf16 MFMA)
  k_gemm_mfma<0><<<dim3(H1_ / 128, M_ / 128), 256, 0, stream>>>(
      roiB, w1t, b1, g1, bb1, rm1, rv1, h1, M_, F_, H1_);
  k_gemm_mfma<0><<<dim3(H2_ / 128, M_ / 128), 256, 0, stream>>>(
      h1, w2t, b2, g2, bb2, rm2, rv2, h2, M_, H1_, H2_);
  k_gemm_mfma<1><<<dim3(H3_ / 128, M_ / 128), 256, 0, stream>>>(
      h2, w3t, b3, nullptr, nullptr, nullptr, nullptr, (short*)h3, M_, H1_ / 2, H3_);

  k_node_head<<<M_ / 256, 256, 0, stream>>>(h3, niw, nib, out_node);
}

// Round 5
// 274.514 us; speedup vs baseline: 1.0693x; 1.0693x over previous
//
#include <hip/hip_runtime.h>
#include <cstdint>
#include <cstddef>

#define BN_EPSF 1e-5f

constexpr int B_  = 32, N_ = 512, F_ = 1024, E_ = 32768;
constexpr int H1_ = 512, H2_ = 256, H3_ = 128, NC_ = 8, EC_ = 10;
constexpr int M_  = B_ * N_;      // 16384 node rows
constexpr int NE_ = B_ * E_;      // 1048576 edges

typedef short bf16x8 __attribute__((ext_vector_type(8)));
typedef float f32x4  __attribute__((ext_vector_type(4)));

__device__ __forceinline__ short f2bf(float f) {
  union { float f; unsigned u; } v; v.f = f;
  unsigned r = v.u + 0x7fffu + ((v.u >> 16) & 1u);   // RNE
  return (short)(r >> 16);
}
// RNE-round two floats to bf16 and pack into one u32 (a -> low, b -> high)
__device__ __forceinline__ unsigned rnepack(float a, float b) {
  unsigned ua = __float_as_uint(a); ua = ua + 0x7fffu + ((ua >> 16) & 1u);
  unsigned ub = __float_as_uint(b); ub = ub + 0x7fffu + ((ub >> 16) & 1u);
  return __builtin_amdgcn_perm(ub, ua, 0x07060302u);  // [ua.hi16 | ub.hi16]
}

#define GLDS(gp, lp) __builtin_amdgcn_global_load_lds( \
    (const __attribute__((address_space(1))) void*)(gp), \
    (__attribute__((address_space(3))) void*)(lp), 16, 0, 0)

// ---------------------------------------------------------------------------
// fused prep: roi fp32->bf16 | 3x weight transpose+convert | node-attr pack
// ---------------------------------------------------------------------------
__device__ __forceinline__ void wt_body(
    const float* __restrict__ W, short* __restrict__ Wt, int K, int N,
    int bx, int by, float (*s)[33])
{
  const int tx = threadIdx.x & 31, ty = threadIdx.x >> 5;
  const int k0 = by * 32, n0 = bx * 32;
#pragma unroll
  for (int r = 0; r < 4; r++)
    s[ty * 4 + r][tx] = W[(size_t)(k0 + ty * 4 + r) * N + n0 + tx];
  __syncthreads();
#pragma unroll
  for (int r = 0; r < 4; r++)
    Wt[(size_t)(n0 + ty * 4 + r) * K + k0 + tx] = f2bf(s[tx][ty * 4 + r]);
}

__global__ __launch_bounds__(256) void k_prep(
    const float* __restrict__ roi, ushort* __restrict__ roiB,
    const float* __restrict__ w1, short* __restrict__ w1t,
    const float* __restrict__ w2, short* __restrict__ w2t,
    const float* __restrict__ w3, short* __restrict__ w3t,
    const float* __restrict__ bbox, const float* __restrict__ dir,
    const float* __restrict__ pri, float* __restrict__ na)
{
  __shared__ float s[32][33];
  const int bx = blockIdx.x;
  if (bx < 8192) {                       // roi -> bf16, 8 elems/thread
    int i = bx * 256 + threadIdx.x;
    float4 a = *(const float4*)(roi + (size_t)i * 8);
    float4 b = *(const float4*)(roi + (size_t)i * 8 + 4);
    unsigned o[4];
    o[0] = rnepack(a.x, a.y); o[1] = rnepack(a.z, a.w);
    o[2] = rnepack(b.x, b.y); o[3] = rnepack(b.z, b.w);
    *(uint4*)(roiB + (size_t)i * 8) = *(uint4*)o;
  } else if (bx < 8704) {                // w1t: K=1024 N=512
    int idx = bx - 8192; wt_body(w1, w1t, F_, H1_, idx & 15, idx >> 4, s);
  } else if (bx < 8832) {                // w2t: K=512 N=256
    int idx = bx - 8704; wt_body(w2, w2t, H1_, H2_, idx & 7, idx >> 3, s);
  } else if (bx < 8864) {                // w3t: K=256 N=128
    int idx = bx - 8832; wt_body(w3, w3t, H2_, H3_, idx & 3, idx >> 2, s);
  } else {                               // node attrs -> float stride 12
    int i = (bx - 8864) * 256 + threadIdx.x;
    float4 b = *(const float4*)(bbox + (size_t)i * 4);
    float4 d = *(const float4*)(dir + (size_t)i * 4);
    float p = pri[i];
    const float inv = 1.0f / 1024.0f;
    float* o = na + (size_t)i * 12;
    *(float4*)(o + 0) = make_float4(b.x * inv, b.y * inv, b.z * inv, b.w * inv);
    *(float4*)(o + 4) = make_float4(d.x, d.y, d.z, d.w);
    *(float4*)(o + 8) = make_float4(p, 0.f, 0.f, 0.f);
  }
}

// ---------------------------------------------------------------------------
// fused node MLP: relu(bn1(x@W1)) -> relu(bn2(@W2)) -> relu(@W3) -> sigmoid
// head. 32 rows/block, 512 blocks (2/CU). h1 computed in 128-col chunks and
// folded straight into the L2 accumulator (h2 lives in registers); h1c/h2/h3
// round-trip through LDS only. All staged tiles are [chunk][row][32] with
// 64B row stride (2-way LDS aliasing = free).
// ---------------------------------------------------------------------------
__global__ __launch_bounds__(256) void k_node_fused(
    const short* __restrict__ roiB, const short* __restrict__ w1t,
    const short* __restrict__ w2t, const short* __restrict__ w3t,
    const float* __restrict__ b1, const float* __restrict__ g1,
    const float* __restrict__ bb1, const float* __restrict__ rm1,
    const float* __restrict__ rv1,
    const float* __restrict__ b2, const float* __restrict__ g2,
    const float* __restrict__ bb2, const float* __restrict__ rm2,
    const float* __restrict__ rv2,
    const float* __restrict__ b3, const float* __restrict__ niw,
    const float* __restrict__ nib, float* __restrict__ out)
{
  __shared__ short sA[2 * 32 * 32];     // 4 KB   A k-tile [c][32][32]
  __shared__ short sStage[256 * 32];    // 16 KB  B staging
  __shared__ short sH1c[32 * 136];      // 8.5 KB h1 chunk (later h3)
  __shared__ short sH2[32 * 264];       // 16.5 KB

  const int tid  = threadIdx.x;
  const int wave = tid >> 6, lane = tid & 63;
  const int lm = lane & 15, q = lane >> 4;
  const int wm = wave >> 1, wn = wave & 1;
  const int m0 = blockIdx.x * 32;

  const int srow2 = tid >> 2;           // 0..63
  const int skq2  = (tid & 3) * 8;

  f32x4 acc2[8] = {};                   // h2: rows wm*16+., cols wn*128+.

  for (int n1 = 0; n1 < 4; n1++) {
    f32x4 acc1[4] = {};
    for (int k0 = 0; k0 < 1024; k0 += 64) {
      {  // A: 32 rows x 64 k -> [c][row][32]; c = tid>>7
        int c = tid >> 7, row = (tid >> 2) & 31;
        GLDS(roiB + (size_t)(m0 + row) * 1024 + k0 + c * 32 + skq2,
             (char*)sA + wave * 1024);
      }
#pragma unroll
      for (int it = 0; it < 2; it++)     // B1: 128 rows x 64 k
#pragma unroll
        for (int c = 0; c < 2; c++)
          GLDS(w1t + (size_t)(n1 * 128 + it * 64 + srow2) * 1024 + k0 + c * 32 + skq2,
               (char*)sStage + c * 8192 + it * 4096 + wave * 1024);
      __syncthreads();

      bf16x8 af[2];
      af[0] = *(const bf16x8*)&sA[(wm * 16 + lm) * 32 + q * 8];
      af[1] = *(const bf16x8*)&sA[1024 + (wm * 16 + lm) * 32 + q * 8];
#pragma unroll
      for (int nt = 0; nt < 4; nt++)
#pragma unroll
        for (int c = 0; c < 2; c++) {
          bf16x8 bfr = *(const bf16x8*)&sStage[c * 4096 + (wn * 64 + nt * 16 + lm) * 32 + q * 8];
          acc1[nt] = __builtin_amdgcn_mfma_f32_16x16x32_bf16(af[c], bfr, acc1[nt], 0, 0, 0);
        }
      __syncthreads();
    }
    // epilogue 1: bias+bn1+relu -> sH1c (local cols 0..127, stride 136)
#pragma unroll
    for (int nt = 0; nt < 4; nt++) {
      int cl = wn * 64 + nt * 16 + lm;
      int col = n1 * 128 + cl;
      float s = g1[col] * rsqrtf(rv1[col] + BN_EPSF);
      float t = bb1[col] - rm1[col] * s;
      float bi = b1[col];
#pragma unroll
      for (int r = 0; r < 4; r++) {
        float v = fmaf(acc1[nt][r] + bi, s, t);
        sH1c[(wm * 16 + q * 4 + r) * 136 + cl] = f2bf(fmaxf(v, 0.f));
      }
    }
    __syncthreads();
    // fold chunk into L2 accumulator: K-range n1*128..+128
    for (int kc = 0; kc < 4; kc++) {
#pragma unroll
      for (int it = 0; it < 4; it++)     // B2: 256 rows x 32 k
        GLDS(w2t + (size_t)(it * 64 + srow2) * 512 + n1 * 128 + kc * 32 + skq2,
             (char*)sStage + it * 4096 + wave * 1024);
      __syncthreads();
      bf16x8 af2 = *(const bf16x8*)&sH1c[(wm * 16 + lm) * 136 + kc * 32 + q * 8];
#pragma unroll
      for (int nt = 0; nt < 8; nt++) {
        bf16x8 bfr = *(const bf16x8*)&sStage[(wn * 128 + nt * 16 + lm) * 32 + q * 8];
        acc2[nt] = __builtin_amdgcn_mfma_f32_16x16x32_bf16(af2, bfr, acc2[nt], 0, 0, 0);
      }
      __syncthreads();
    }
  }

  // epilogue 2: bias+bn2+relu -> sH2 (stride 264)
#pragma unroll
  for (int nt = 0; nt < 8; nt++) {
    int col = wn * 128 + nt * 16 + lm;
    float s = g2[col] * rsqrtf(rv2[col] + BN_EPSF);
    float t = bb2[col] - rm2[col] * s;
    float bi = b2[col];
#pragma unroll
    for (int r = 0; r < 4; r++) {
      float v = fmaf(acc2[nt][r] + bi, s, t);
      sH2[(wm * 16 + q * 4 + r) * 264 + col] = f2bf(fmaxf(v, 0.f));
    }
  }
  __syncthreads();

  // phase 3: h3 = relu(h2 @ W3 + b3), K=256, out 32x128
  f32x4 acc3[4] = {};
  for (int k0 = 0; k0 < 256; k0 += 64) {
#pragma unroll
    for (int it = 0; it < 2; it++)       // B3: 128 rows x 64 k
#pragma unroll
      for (int c = 0; c < 2; c++)
        GLDS(w3t + (size_t)(it * 64 + srow2) * 256 + k0 + c * 32 + skq2,
             (char*)sStage + c * 8192 + it * 4096 + wave * 1024);
    __syncthreads();
#pragma unroll
    for (int c = 0; c < 2; c++) {
      bf16x8 af3 = *(const bf16x8*)&sH2[(wm * 16 + lm) * 264 + k0 + c * 32 + q * 8];
#pragma unroll
      for (int nt = 0; nt < 4; nt++) {
        bf16x8 bfr = *(const bf16x8*)&sStage[c * 4096 + (wn * 64 + nt * 16 + lm) * 32 + q * 8];
        acc3[nt] = __builtin_amdgcn_mfma_f32_16x16x32_bf16(af3, bfr, acc3[nt], 0, 0, 0);
      }
    }
    __syncthreads();
  }
  short* sH3 = sH1c;                    // sH1c dead after phase 2
#pragma unroll
  for (int nt = 0; nt < 4; nt++) {
    int col = wn * 64 + nt * 16 + lm;
    float bi = b3[col];
#pragma unroll
    for (int r = 0; r < 4; r++) {
      float v = acc3[nt][r] + bi;
      sH3[(wm * 16 + q * 4 + r) * 136 + col] = f2bf(fmaxf(v, 0.f));
    }
  }
  __syncthreads();

  // phase 4: head sigmoid(h3 @ ni_w + ni_b), waves 0,1 take 16 rows each
  if (wave < 2) {
    f32x4 a4 = {};
#pragma unroll
    for (int c = 0; c < 4; c++) {
      ushort tmp[8];
#pragma unroll
      for (int j = 0; j < 8; j++) {
        int k = c * 32 + q * 8 + j;
        tmp[j] = (lm < 8) ? (ushort)f2bf(niw[k * 8 + lm]) : (ushort)0;
      }
      bf16x8 fw = *(bf16x8*)tmp;
      bf16x8 af4 = *(const bf16x8*)&sH3[(wave * 16 + lm) * 136 + c * 32 + q * 8];
      a4 = __builtin_amdgcn_mfma_f32_16x16x32_bf16(af4, fw, a4, 0, 0, 0);
    }
    if (lm < 8) {
      float bi = nib[lm];
#pragma unroll
      for (int r = 0; r < 4; r++) {
        float v = a4[r] + bi;
        out[(size_t)(m0 + wave * 16 + q * 4 + r) * 8 + lm] = 1.f / (1.f + __expf(-v));
      }
    }
  }
}

// ---------------------------------------------------------------------------
// MFMA edge MLP (round-3 version, 56 us known-good): gather 2x9 attrs (bf16)
// -> 18 -> 64 relu -> 64 relu -> 10 sig. Weights in VGPR B-fragments; layer
// outputs round-trip through LDS (C-layout -> A-layout).
// ---------------------------------------------------------------------------
__global__ __launch_bounds__(256, 2) void k_edge_mfma(
    const float* __restrict__ na, const int* __restrict__ eidx,
    const float* __restrict__ w1, const float* __restrict__ b1,
    const float* __restrict__ w2, const float* __restrict__ b2,
    const float* __restrict__ wo, const float* __restrict__ bo,
    float* __restrict__ out)
{
  __shared__ __align__(16) short sA[9216];      // W-stage(7168) / X(128x40) / H2(128x72)
  __shared__ __align__(16) short sH1[128 * 72]; // 18 KB
  __shared__ float sB[144];                     // b1[64] b2[64] bo[16]

  const int tid  = threadIdx.x;
  const int wave = tid >> 6, lane = tid & 63;
  const int lm  = lane & 15;
  const int lk8 = (lane >> 4) * 8;
  const int lr  = (lane >> 4) * 4;

  short* sW1 = sA;            // 64 x 32
  short* sW2 = sA + 2048;     // 64 x 64
  short* sW3 = sA + 6144;     // 16 x 64 (rows 10..15 zero)
  short* sX  = sA;            // 128 x 40
  short* sH2 = sA;            // 128 x 72

  for (int i = tid; i < 2048; i += 256) {
    int n = i >> 5, k = i & 31;
    sW1[i] = (k < 18) ? f2bf(w1[k * 64 + n]) : (short)0;
  }
  for (int i = tid; i < 4096; i += 256) {
    int n = i >> 6, k = i & 63;
    sW2[i] = f2bf(w2[k * 64 + n]);
  }
  for (int i = tid; i < 1024; i += 256) {
    int n = i >> 6, k = i & 63;
    sW3[i] = (n < 10) ? f2bf(wo[k * 10 + n]) : (short)0;
  }
  if (tid < 64) { sB[tid] = b1[tid]; sB[64 + tid] = b2[tid]; }
  if (tid < 16) sB[128 + tid] = (tid < 10) ? bo[tid] : 0.f;
  __syncthreads();

  bf16x8 fW1[4], fW2[4][2], fW3[2];
#pragma unroll
  for (int t = 0; t < 4; t++)
    fW1[t] = *(const bf16x8*)&sW1[(t * 16 + lm) * 32 + lk8];
#pragma unroll
  for (int t = 0; t < 4; t++)
#pragma unroll
    for (int ks = 0; ks < 2; ks++)
      fW2[t][ks] = *(const bf16x8*)&sW2[(t * 16 + lm) * 64 + ks * 32 + lk8];
#pragma unroll
  for (int ks = 0; ks < 2; ks++)
    fW3[ks] = *(const bf16x8*)&sW3[lm * 64 + ks * 32 + lk8];
  float bias1v[4], bias2v[4];
#pragma unroll
  for (int t = 0; t < 4; t++) {
    bias1v[t] = sB[t * 16 + lm];
    bias2v[t] = sB[64 + t * 16 + lm];
  }
  const float biasOv = sB[128 + lm];
  __syncthreads();

  for (int bi = 0; bi < 8; bi++) {
    const int e0 = (blockIdx.x * 8 + bi) * 128;

    if (tid < 128) {
      int e = e0 + tid;
      int b = e >> 15, kk = e & (E_ - 1);
      const int* ei = eidx + (size_t)b * 2 * E_;
      int s = ei[kk], d = ei[E_ + kk];
      const float* ps = na + ((size_t)b * N_ + s) * 12;
      const float* pd = na + ((size_t)b * N_ + d) * 12;
      float4 a0 = *(const float4*)(ps);
      float4 a1 = *(const float4*)(ps + 4);
      float  a2 = ps[8];
      float4 c0 = *(const float4*)(pd);
      float4 c1 = *(const float4*)(pd + 4);
      float  c2 = pd[8];
      ushort xr[32];
      xr[0] = (ushort)f2bf(a0.x); xr[1] = (ushort)f2bf(a0.y);
      xr[2] = (ushort)f2bf(a0.z); xr[3] = (ushort)f2bf(a0.w);
      xr[4] = (ushort)f2bf(a1.x); xr[5] = (ushort)f2bf(a1.y);
      xr[6] = (ushort)f2bf(a1.z); xr[7] = (ushort)f2bf(a1.w);
      xr[8] = (ushort)f2bf(a2);
      xr[9]  = (ushort)f2bf(c0.x); xr[10] = (ushort)f2bf(c0.y);
      xr[11] = (ushort)f2bf(c0.z); xr[12] = (ushort)f2bf(c0.w);
      xr[13] = (ushort)f2bf(c1.x); xr[14] = (ushort)f2bf(c1.y);
      xr[15] = (ushort)f2bf(c1.z); xr[16] = (ushort)f2bf(c1.w);
      xr[17] = (ushort)f2bf(c2);
#pragma unroll
      for (int i = 18; i < 32; i++) xr[i] = 0;
      ushort* row = (ushort*)&sX[tid * 40];
      *(uint4*)(row + 0)  = *(uint4*)&xr[0];
      *(uint4*)(row + 8)  = *(uint4*)&xr[8];
      *(uint4*)(row + 16) = *(uint4*)&xr[16];
      *(uint4*)(row + 24) = *(uint4*)&xr[24];
    }
    __syncthreads();

    bf16x8 a1f[2];
#pragma unroll
    for (int ti = 0; ti < 2; ti++)
      a1f[ti] = *(const bf16x8*)&sX[(wave * 32 + ti * 16 + lm) * 40 + lk8];
    f32x4 acc1[2][4] = {};
#pragma unroll
    for (int ti = 0; ti < 2; ti++)
#pragma unroll
      for (int tj = 0; tj < 4; tj++)
        acc1[ti][tj] = __builtin_amdgcn_mfma_f32_16x16x32_bf16(
            a1f[ti], fW1[tj], acc1[ti][tj], 0, 0, 0);
#pragma unroll
    for (int ti = 0; ti < 2; ti++)
#pragma unroll
      for (int tj = 0; tj < 4; tj++)
#pragma unroll
        for (int r = 0; r < 4; r++) {
          int row = wave * 32 + ti * 16 + lr + r;
          float v = acc1[ti][tj][r] + bias1v[tj];
          sH1[row * 72 + tj * 16 + lm] = f2bf(fmaxf(v, 0.f));
        }
    __syncthreads();

    bf16x8 a2f[2][2];
#pragma unroll
    for (int ti = 0; ti < 2; ti++)
#pragma unroll
      for (int ks = 0; ks < 2; ks++)
        a2f[ti][ks] = *(const bf16x8*)&sH1[(wave * 32 + ti * 16 + lm) * 72 + ks * 32 + lk8];
    f32x4 acc2[2][4] = {};
#pragma unroll
    for (int ks = 0; ks < 2; ks++)
#pragma unroll
      for (int ti = 0; ti < 2; ti++)
#pragma unroll
        for (int tj = 0; tj < 4; tj++)
          acc2[ti][tj] = __builtin_amdgcn_mfma_f32_16x16x32_bf16(
              a2f[ti][ks], fW2[tj][ks], acc2[ti][tj], 0, 0, 0);
#pragma unroll
    for (int ti = 0; ti < 2; ti++)
#pragma unroll
      for (int tj = 0; tj < 4; tj++)
#pragma unroll
        for (int r = 0; r < 4; r++) {
          int row = wave * 32 + ti * 16 + lr + r;
          float v = acc2[ti][tj][r] + bias2v[tj];
          sH2[row * 72 + tj * 16 + lm] = f2bf(fmaxf(v, 0.f));
        }

    bf16x8 a3f[2][2];
#pragma unroll
    for (int ti = 0; ti < 2; ti++)
#pragma unroll
      for (int ks = 0; ks < 2; ks++)
        a3f[ti][ks] = *(const bf16x8*)&sH2[(wave * 32 + ti * 16 + lm) * 72 + ks * 32 + lk8];
    f32x4 acc3[2] = {};
#pragma unroll
    for (int ks = 0; ks < 2; ks++)
#pragma unroll
      for (int ti = 0; ti < 2; ti++)
        acc3[ti] = __builtin_amdgcn_mfma_f32_16x16x32_bf16(
            a3f[ti][ks], fW3[ks], acc3[ti], 0, 0, 0);
    if (lm < 10) {
#pragma unroll
      for (int ti = 0; ti < 2; ti++)
#pragma unroll
        for (int r = 0; r < 4; r++) {
          int row = wave * 32 + ti * 16 + lr + r;
          float v = acc3[ti][r] + biasOv;
          out[(size_t)(e0 + row) * 10 + lm] = 1.f / (1.f + __expf(-v));
        }
    }
    __syncthreads();
  }
}

// ---------------------------------------------------------------------------
extern "C" void kernel_launch(void* const* d_in, const int* in_sizes, int n_in,
                              void* d_out, int out_size, void* d_ws, size_t ws_size,
                              hipStream_t stream)
{
  const float* roi   = (const float*)d_in[0];
  const float* bbox  = (const float*)d_in[1];
  const float* dir   = (const float*)d_in[2];
  const float* pri   = (const float*)d_in[3];
  const int*   eidx  = (const int*)d_in[4];
  const float* w1    = (const float*)d_in[5];
  const float* b1    = (const float*)d_in[6];
  const float* g1    = (const float*)d_in[7];
  const float* bb1   = (const float*)d_in[8];
  const float* rm1   = (const float*)d_in[9];
  const float* rv1   = (const float*)d_in[10];
  const float* w2    = (const float*)d_in[11];
  const float* b2    = (const float*)d_in[12];
  const float* g2    = (const float*)d_in[13];
  const float* bb2   = (const float*)d_in[14];
  const float* rm2   = (const float*)d_in[15];
  const float* rv2   = (const float*)d_in[16];
  const float* w3    = (const float*)d_in[17];
  const float* b3    = (const float*)d_in[18];
  const float* niw   = (const float*)d_in[19];
  const float* nib   = (const float*)d_in[20];
  const float* ew1   = (const float*)d_in[21];
  const float* eb1   = (const float*)d_in[22];
  const float* ew2   = (const float*)d_in[23];
  const float* eb2   = (const float*)d_in[24];
  const float* eow   = (const float*)d_in[25];
  const float* eob   = (const float*)d_in[26];

  float* out_node = (float*)d_out;                    // 16384 x 8
  float* out_edge = (float*)d_out + (size_t)M_ * NC_; // 1048576 x 10

  // workspace layout (bytes)
  char* w = (char*)d_ws;
  short*  roiB = (short*)w;                           // 33,554,432
  short*  w1t  = (short*)(w + 33554432);              //  1,048,576
  short*  w2t  = (short*)(w + 34603008);              //    262,144
  short*  w3t  = (short*)(w + 34865152);              //     65,536
  float*  na   = (float*)(w + 34930688);              //    786,432

  // fused conversions + node-attr pack (1 launch)
  k_prep<<<8928, 256, 0, stream>>>(roi, (ushort*)roiB, w1, w1t, w2, w2t,
                                   w3, w3t, bbox, dir, pri, na);

  // edge MLP (round-3 kernel)
  k_edge_mfma<<<NE_ / 1024, 256, 0, stream>>>(
      na, eidx, ew1, eb1, ew2, eb2, eow, eob, out_edge);

  // fully fused node MLP + head (1 launch)
  k_node_fused<<<M_ / 32, 256, 0, stream>>>(
      roiB, w1t, w2t, w3t,
      b1, g1, bb1, rm1, rv1,
      b2, g2, bb2, rm2, rv2,
      b3, niw, nib, out_node);
}

// Round 6
// 267.768 us; speedup vs baseline: 1.0963x; 1.0252x over previous
//
#include <hip/hip_runtime.h>
#include <cstdint>
#include <cstddef>

#define BN_EPSF 1e-5f

constexpr int B_  = 32, N_ = 512, F_ = 1024, E_ = 32768;
constexpr int H1_ = 512, H2_ = 256, H3_ = 128, NC_ = 8, EC_ = 10;
constexpr int M_  = B_ * N_;      // 16384 node rows
constexpr int NE_ = B_ * E_;      // 1048576 edges

typedef short bf16x8 __attribute__((ext_vector_type(8)));
typedef float f32x4  __attribute__((ext_vector_type(4)));

__device__ __forceinline__ short f2bf(float f) {
  union { float f; unsigned u; } v; v.f = f;
  unsigned r = v.u + 0x7fffu + ((v.u >> 16) & 1u);   // RNE
  return (short)(r >> 16);
}
// RNE-round two floats to bf16 and pack into one u32 (a -> low, b -> high)
__device__ __forceinline__ unsigned rnepack(float a, float b) {
  unsigned ua = __float_as_uint(a); ua = ua + 0x7fffu + ((ua >> 16) & 1u);
  unsigned ub = __float_as_uint(b); ub = ub + 0x7fffu + ((ub >> 16) & 1u);
  return __builtin_amdgcn_perm(ub, ua, 0x07060302u);  // [ua.hi16 | ub.hi16]
}

#define GLDS(gp, lp) __builtin_amdgcn_global_load_lds( \
    (const __attribute__((address_space(1))) void*)(gp), \
    (__attribute__((address_space(3))) void*)(lp), 16, 0, 0)

#define MFMA(a, b, c) __builtin_amdgcn_mfma_f32_16x16x32_bf16((a), (b), (c), 0, 0, 0)

// ---------------------------------------------------------------------------
// fused prep: roi fp32->bf16 | 3x weight transpose+convert | node-attr pack
// ---------------------------------------------------------------------------
__device__ __forceinline__ void wt_body(
    const float* __restrict__ W, short* __restrict__ Wt, int K, int N,
    int bx, int by, float (*s)[33])
{
  const int tx = threadIdx.x & 31, ty = threadIdx.x >> 5;
  const int k0 = by * 32, n0 = bx * 32;
#pragma unroll
  for (int r = 0; r < 4; r++)
    s[ty * 4 + r][tx] = W[(size_t)(k0 + ty * 4 + r) * N + n0 + tx];
  __syncthreads();
#pragma unroll
  for (int r = 0; r < 4; r++)
    Wt[(size_t)(n0 + ty * 4 + r) * K + k0 + tx] = f2bf(s[tx][ty * 4 + r]);
}

__global__ __launch_bounds__(256) void k_prep(
    const float* __restrict__ roi, ushort* __restrict__ roiB,
    const float* __restrict__ w1, short* __restrict__ w1t,
    const float* __restrict__ w2, short* __restrict__ w2t,
    const float* __restrict__ w3, short* __restrict__ w3t,
    const float* __restrict__ bbox, const float* __restrict__ dir,
    const float* __restrict__ pri, float* __restrict__ na)
{
  __shared__ float s[32][33];
  const int bx = blockIdx.x;
  if (bx < 8192) {                       // roi -> bf16, 8 elems/thread
    int i = bx * 256 + threadIdx.x;
    float4 a = *(const float4*)(roi + (size_t)i * 8);
    float4 b = *(const float4*)(roi + (size_t)i * 8 + 4);
    unsigned o[4];
    o[0] = rnepack(a.x, a.y); o[1] = rnepack(a.z, a.w);
    o[2] = rnepack(b.x, b.y); o[3] = rnepack(b.z, b.w);
    *(uint4*)(roiB + (size_t)i * 8) = *(uint4*)o;
  } else if (bx < 8704) {                // w1t: K=1024 N=512
    int idx = bx - 8192; wt_body(w1, w1t, F_, H1_, idx & 15, idx >> 4, s);
  } else if (bx < 8832) {                // w2t: K=512 N=256
    int idx = bx - 8704; wt_body(w2, w2t, H1_, H2_, idx & 7, idx >> 3, s);
  } else if (bx < 8864) {                // w3t: K=256 N=128
    int idx = bx - 8832; wt_body(w3, w3t, H2_, H3_, idx & 3, idx >> 2, s);
  } else {                               // node attrs -> float stride 12
    int i = (bx - 8864) * 256 + threadIdx.x;
    float4 b = *(const float4*)(bbox + (size_t)i * 4);
    float4 d = *(const float4*)(dir + (size_t)i * 4);
    float p = pri[i];
    const float inv = 1.0f / 1024.0f;
    float* o = na + (size_t)i * 12;
    *(float4*)(o + 0) = make_float4(b.x * inv, b.y * inv, b.z * inv, b.w * inv);
    *(float4*)(o + 4) = make_float4(d.x, d.y, d.z, d.w);
    *(float4*)(o + 8) = make_float4(p, 0.f, 0.f, 0.f);
  }
}

// ---------------------------------------------------------------------------
// L1 GEMM (m97 structure, r2-proven): h1 = relu(bn1(roiB @ W1 + b1))
// 128x128 tile, BK=32, 256 thr (4 waves 2x2), 4x4 mfma_16x16x32 per wave.
// ---------------------------------------------------------------------------
__global__ __launch_bounds__(256) void k_gemm_l1(
    const short* __restrict__ A, const short* __restrict__ Wt,
    const float* __restrict__ bias,
    const float* __restrict__ g, const float* __restrict__ bb,
    const float* __restrict__ rm, const float* __restrict__ rv,
    short* __restrict__ C, int M, int K, int N)
{
  __shared__ short As[128 * 32];
  __shared__ short Bs[128 * 32];

  const int tid  = threadIdx.x;
  const int wave = tid >> 6, lane = tid & 63;
  const int m0 = blockIdx.y * 128, n0 = blockIdx.x * 128;
  const int wm = wave >> 1, wn = wave & 1;

  const int arow = tid >> 2;
  const int akq  = (tid & 3) * 8;

  f32x4 acc[4][4] = {};

  for (int k0 = 0; k0 < K; k0 += 32) {
#pragma unroll
    for (int it = 0; it < 2; it++)
      GLDS(A + (size_t)(m0 + it * 64 + arow) * K + k0 + akq,
           (char*)As + it * 4096 + wave * 1024);
#pragma unroll
    for (int it = 0; it < 2; it++)
      GLDS(Wt + (size_t)(n0 + it * 64 + arow) * K + k0 + akq,
           (char*)Bs + it * 4096 + wave * 1024);
    __syncthreads();

    const int ko = (lane >> 4) * 8;
    bf16x8 af[4], bfr[4];
#pragma unroll
    for (int t = 0; t < 4; t++) {
      af[t]  = *(const bf16x8*)&As[(wm * 64 + t * 16 + (lane & 15)) * 32 + ko];
      bfr[t] = *(const bf16x8*)&Bs[(wn * 64 + t * 16 + (lane & 15)) * 32 + ko];
    }
#pragma unroll
    for (int ti = 0; ti < 4; ti++)
#pragma unroll
      for (int tj = 0; tj < 4; tj++)
        acc[ti][tj] = MFMA(af[ti], bfr[tj], acc[ti][tj]);
    __syncthreads();
  }

#pragma unroll
  for (int tj = 0; tj < 4; tj++) {
    const int col = n0 + wn * 64 + tj * 16 + (lane & 15);
    const float bi = bias[col];
    float s = g[col] * rsqrtf(rv[col] + BN_EPSF);
    float t = bb[col] - rm[col] * s;
#pragma unroll
    for (int ti = 0; ti < 4; ti++) {
      const int rbase = m0 + wm * 64 + ti * 16 + ((lane >> 4) << 2);
#pragma unroll
      for (int r = 0; r < 4; r++) {
        float v = fmaf(acc[ti][tj][r] + bi, s, t);
        C[(size_t)(rbase + r) * N + col] = f2bf(fmaxf(v, 0.f));
      }
    }
  }
}

// ---------------------------------------------------------------------------
// fused tail: h2 = relu(bn2(h1@W2)), h3 = relu(h2@W3), out = sigmoid(h3@niw)
// 512 blocks x 32 rows, 4 waves (2x2). BK=64 staging, 16 MFMA/wave/barrier
// in phase 2. LDS arena 53 KB -> 3 blocks/CU. ~26 barriers/block total.
// ---------------------------------------------------------------------------
__global__ __launch_bounds__(256) void k_tail(
    const short* __restrict__ h1, const short* __restrict__ w2t,
    const short* __restrict__ w3t,
    const float* __restrict__ b2, const float* __restrict__ g2,
    const float* __restrict__ bb2, const float* __restrict__ rm2,
    const float* __restrict__ rv2,
    const float* __restrict__ b3, const float* __restrict__ niw,
    const float* __restrict__ nib, float* __restrict__ out)
{
  __shared__ __align__(16) char arena[53760];
  short* sA  = (short*)arena;              // [c2][32][32]   4 KB  (phase 2)
  short* sB  = (short*)(arena + 4096);     // [c2][256][32] 32 KB  (phase 2)
  short* sH2 = (short*)(arena + 36864);    // 32 x 264      16.9 KB
  short* sB3 = (short*)arena;              // [c2][128][32] 16 KB  (phase 3)
  short* sH3 = (short*)(arena + 16384);    // 32 x 136       8.7 KB

  const int tid  = threadIdx.x;
  const int wave = tid >> 6, lane = tid & 63;
  const int lm = lane & 15, q = lane >> 4;
  const int wm = wave >> 1, wn = wave & 1;
  const int m0 = blockIdx.x * 32;
  const int srow = tid >> 2;          // 0..63
  const int skq  = (tid & 3) * 8;

  // ---- phase 2: h2 = relu(bn2(h1 @ W2 + b2)); rows wm*16+, cols wn*128+ ----
  f32x4 acc2[8] = {};
  for (int k0 = 0; k0 < 512; k0 += 64) {
    {  // A: 32 rows x 64 k -> [c][32][32]; c = tid>>7
      int c = tid >> 7, row = (tid >> 2) & 31;
      GLDS(h1 + (size_t)(m0 + row) * 512 + k0 + c * 32 + skq,
           (char*)sA + wave * 1024);
    }
#pragma unroll
    for (int it = 0; it < 4; it++)     // B: 256 rows x 64 k -> [c][256][32]
#pragma unroll
      for (int c = 0; c < 2; c++)
        GLDS(w2t + (size_t)(it * 64 + srow) * 512 + k0 + c * 32 + skq,
             (char*)sB + c * 16384 + it * 4096 + wave * 1024);
    __syncthreads();
#pragma unroll
    for (int c = 0; c < 2; c++) {
      bf16x8 af = *(const bf16x8*)&sA[c * 1024 + (wm * 16 + lm) * 32 + q * 8];
#pragma unroll
      for (int nt = 0; nt < 8; nt++) {
        bf16x8 bfr = *(const bf16x8*)&sB[c * 8192 + (wn * 128 + nt * 16 + lm) * 32 + q * 8];
        acc2[nt] = MFMA(af, bfr, acc2[nt]);
      }
    }
    __syncthreads();
  }
#pragma unroll
  for (int nt = 0; nt < 8; nt++) {
    int col = wn * 128 + nt * 16 + lm;
    float s = g2[col] * rsqrtf(rv2[col] + BN_EPSF);
    float t = bb2[col] - rm2[col] * s;
    float bi = b2[col];
#pragma unroll
    for (int r = 0; r < 4; r++) {
      float v = fmaf(acc2[nt][r] + bi, s, t);
      sH2[(wm * 16 + q * 4 + r) * 264 + col] = f2bf(fmaxf(v, 0.f));
    }
  }
  __syncthreads();

  // ---- phase 3: h3 = relu(h2 @ W3 + b3); rows wm*16+, cols wn*64+ ----
  f32x4 acc3[4] = {};
  for (int k0 = 0; k0 < 256; k0 += 64) {
#pragma unroll
    for (int it = 0; it < 2; it++)     // B3: 128 rows x 64 k -> [c][128][32]
#pragma unroll
      for (int c = 0; c < 2; c++)
        GLDS(w3t + (size_t)(it * 64 + srow) * 256 + k0 + c * 32 + skq,
             (char*)sB3 + c * 8192 + it * 4096 + wave * 1024);
    __syncthreads();
#pragma unroll
    for (int c = 0; c < 2; c++) {
      bf16x8 af = *(const bf16x8*)&sH2[(wm * 16 + lm) * 264 + k0 + c * 32 + q * 8];
#pragma unroll
      for (int nt = 0; nt < 4; nt++) {
        bf16x8 bfr = *(const bf16x8*)&sB3[c * 4096 + (wn * 64 + nt * 16 + lm) * 32 + q * 8];
        acc3[nt] = MFMA(af, bfr, acc3[nt]);
      }
    }
    __syncthreads();
  }
#pragma unroll
  for (int nt = 0; nt < 4; nt++) {
    int col = wn * 64 + nt * 16 + lm;
    float bi = b3[col];
#pragma unroll
    for (int r = 0; r < 4; r++) {
      float v = acc3[nt][r] + bi;
      sH3[(wm * 16 + q * 4 + r) * 136 + col] = f2bf(fmaxf(v, 0.f));
    }
  }
  __syncthreads();

  // ---- phase 4: head sigmoid(h3 @ ni_w + ni_b); waves 0,1: 16 rows each ----
  if (wave < 2) {
    f32x4 a4 = {};
#pragma unroll
    for (int c = 0; c < 4; c++) {
      ushort tmp[8];
#pragma unroll
      for (int j = 0; j < 8; j++) {
        int k = c * 32 + q * 8 + j;
        tmp[j] = (lm < 8) ? (ushort)f2bf(niw[k * 8 + lm]) : (ushort)0;
      }
      bf16x8 fw = *(bf16x8*)tmp;
      bf16x8 af4 = *(const bf16x8*)&sH3[(wave * 16 + lm) * 136 + c * 32 + q * 8];
      a4 = MFMA(af4, fw, a4);
    }
    if (lm < 8) {
      float bi = nib[lm];
#pragma unroll
      for (int r = 0; r < 4; r++) {
        float v = a4[r] + bi;
        out[(size_t)(m0 + wave * 16 + q * 4 + r) * 8 + lm] = 1.f / (1.f + __expf(-v));
      }
    }
  }
}

// ---------------------------------------------------------------------------
// MFMA edge MLP (r3-proven): gather 2x9 attrs (bf16) -> 18 -> 64 relu ->
// 64 relu -> 10 sig. Weights in VGPR B-fragments; layer outputs round-trip
// through LDS. Re-gridded: 2048 blocks x 4 batches of 128 edges.
// ---------------------------------------------------------------------------
__global__ __launch_bounds__(256, 2) void k_edge_mfma(
    const float* __restrict__ na, const int* __restrict__ eidx,
    const float* __restrict__ w1, const float* __restrict__ b1,
    const float* __restrict__ w2, const float* __restrict__ b2,
    const float* __restrict__ wo, const float* __restrict__ bo,
    float* __restrict__ out)
{
  __shared__ __align__(16) short sA[9216];      // W-stage(7168) / X(128x40) / H2(128x72)
  __shared__ __align__(16) short sH1[128 * 72]; // 18 KB
  __shared__ float sB[144];                     // b1[64] b2[64] bo[16]

  const int tid  = threadIdx.x;
  const int wave = tid >> 6, lane = tid & 63;
  const int lm  = lane & 15;
  const int lk8 = (lane >> 4) * 8;
  const int lr  = (lane >> 4) * 4;

  short* sW1 = sA;            // 64 x 32
  short* sW2 = sA + 2048;     // 64 x 64
  short* sW3 = sA + 6144;     // 16 x 64 (rows 10..15 zero)
  short* sX  = sA;            // 128 x 40
  short* sH2 = sA;            // 128 x 72

  for (int i = tid; i < 2048; i += 256) {
    int n = i >> 5, k = i & 31;
    sW1[i] = (k < 18) ? f2bf(w1[k * 64 + n]) : (short)0;
  }
  for (int i = tid; i < 4096; i += 256) {
    int n = i >> 6, k = i & 63;
    sW2[i] = f2bf(w2[k * 64 + n]);
  }
  for (int i = tid; i < 1024; i += 256) {
    int n = i >> 6, k = i & 63;
    sW3[i] = (n < 10) ? f2bf(wo[k * 10 + n]) : (short)0;
  }
  if (tid < 64) { sB[tid] = b1[tid]; sB[64 + tid] = b2[tid]; }
  if (tid < 16) sB[128 + tid] = (tid < 10) ? bo[tid] : 0.f;
  __syncthreads();

  bf16x8 fW1[4], fW2[4][2], fW3[2];
#pragma unroll
  for (int t = 0; t < 4; t++)
    fW1[t] = *(const bf16x8*)&sW1[(t * 16 + lm) * 32 + lk8];
#pragma unroll
  for (int t = 0; t < 4; t++)
#pragma unroll
    for (int ks = 0; ks < 2; ks++)
      fW2[t][ks] = *(const bf16x8*)&sW2[(t * 16 + lm) * 64 + ks * 32 + lk8];
#pragma unroll
  for (int ks = 0; ks < 2; ks++)
    fW3[ks] = *(const bf16x8*)&sW3[lm * 64 + ks * 32 + lk8];
  float bias1v[4], bias2v[4];
#pragma unroll
  for (int t = 0; t < 4; t++) {
    bias1v[t] = sB[t * 16 + lm];
    bias2v[t] = sB[64 + t * 16 + lm];
  }
  const float biasOv = sB[128 + lm];
  __syncthreads();

  for (int bi = 0; bi < 4; bi++) {
    const int e0 = (blockIdx.x * 4 + bi) * 128;

    if (tid < 128) {
      int e = e0 + tid;
      int b = e >> 15, kk = e & (E_ - 1);
      const int* ei = eidx + (size_t)b * 2 * E_;
      int s = ei[kk], d = ei[E_ + kk];
      const float* ps = na + ((size_t)b * N_ + s) * 12;
      const float* pd = na + ((size_t)b * N_ + d) * 12;
      float4 a0 = *(const float4*)(ps);
      float4 a1 = *(const float4*)(ps + 4);
      float  a2 = ps[8];
      float4 c0 = *(const float4*)(pd);
      float4 c1 = *(const float4*)(pd + 4);
      float  c2 = pd[8];
      ushort xr[32];
      xr[0] = (ushort)f2bf(a0.x); xr[1] = (ushort)f2bf(a0.y);
      xr[2] = (ushort)f2bf(a0.z); xr[3] = (ushort)f2bf(a0.w);
      xr[4] = (ushort)f2bf(a1.x); xr[5] = (ushort)f2bf(a1.y);
      xr[6] = (ushort)f2bf(a1.z); xr[7] = (ushort)f2bf(a1.w);
      xr[8] = (ushort)f2bf(a2);
      xr[9]  = (ushort)f2bf(c0.x); xr[10] = (ushort)f2bf(c0.y);
      xr[11] = (ushort)f2bf(c0.z); xr[12] = (ushort)f2bf(c0.w);
      xr[13] = (ushort)f2bf(c1.x); xr[14] = (ushort)f2bf(c1.y);
      xr[15] = (ushort)f2bf(c1.z); xr[16] = (ushort)f2bf(c1.w);
      xr[17] = (ushort)f2bf(c2);
#pragma unroll
      for (int i = 18; i < 32; i++) xr[i] = 0;
      ushort* row = (ushort*)&sX[tid * 40];
      *(uint4*)(row + 0)  = *(uint4*)&xr[0];
      *(uint4*)(row + 8)  = *(uint4*)&xr[8];
      *(uint4*)(row + 16) = *(uint4*)&xr[16];
      *(uint4*)(row + 24) = *(uint4*)&xr[24];
    }
    __syncthreads();

    bf16x8 a1f[2];
#pragma unroll
    for (int ti = 0; ti < 2; ti++)
      a1f[ti] = *(const bf16x8*)&sX[(wave * 32 + ti * 16 + lm) * 40 + lk8];
    f32x4 acc1[2][4] = {};
#pragma unroll
    for (int ti = 0; ti < 2; ti++)
#pragma unroll
      for (int tj = 0; tj < 4; tj++)
        acc1[ti][tj] = MFMA(a1f[ti], fW1[tj], acc1[ti][tj]);
#pragma unroll
    for (int ti = 0; ti < 2; ti++)
#pragma unroll
      for (int tj = 0; tj < 4; tj++)
#pragma unroll
        for (int r = 0; r < 4; r++) {
          int row = wave * 32 + ti * 16 + lr + r;
          float v = acc1[ti][tj][r] + bias1v[tj];
          sH1[row * 72 + tj * 16 + lm] = f2bf(fmaxf(v, 0.f));
        }
    __syncthreads();

    bf16x8 a2f[2][2];
#pragma unroll
    for (int ti = 0; ti < 2; ti++)
#pragma unroll
      for (int ks = 0; ks < 2; ks++)
        a2f[ti][ks] = *(const bf16x8*)&sH1[(wave * 32 + ti * 16 + lm) * 72 + ks * 32 + lk8];
    f32x4 acc2[2][4] = {};
#pragma unroll
    for (int ks = 0; ks < 2; ks++)
#pragma unroll
      for (int ti = 0; ti < 2; ti++)
#pragma unroll
        for (int tj = 0; tj < 4; tj++)
          acc2[ti][tj] = MFMA(a2f[ti][ks], fW2[tj][ks], acc2[ti][tj]);
#pragma unroll
    for (int ti = 0; ti < 2; ti++)
#pragma unroll
      for (int tj = 0; tj < 4; tj++)
#pragma unroll
        for (int r = 0; r < 4; r++) {
          int row = wave * 32 + ti * 16 + lr + r;
          float v = acc2[ti][tj][r] + bias2v[tj];
          sH2[row * 72 + tj * 16 + lm] = f2bf(fmaxf(v, 0.f));
        }

    bf16x8 a3f[2][2];
#pragma unroll
    for (int ti = 0; ti < 2; ti++)
#pragma unroll
      for (int ks = 0; ks < 2; ks++)
        a3f[ti][ks] = *(const bf16x8*)&sH2[(wave * 32 + ti * 16 + lm) * 72 + ks * 32 + lk8];
    f32x4 acc3[2] = {};
#pragma unroll
    for (int ks = 0; ks < 2; ks++)
#pragma unroll
      for (int ti = 0; ti < 2; ti++)
        acc3[ti] = MFMA(a3f[ti][ks], fW3[ks], acc3[ti]);
    if (lm < 10) {
#pragma unroll
      for (int ti = 0; ti < 2; ti++)
#pragma unroll
        for (int r = 0; r < 4; r++) {
          int row = wave * 32 + ti * 16 + lr + r;
          float v = acc3[ti][r] + biasOv;
          out[(size_t)(e0 + row) * 10 + lm] = 1.f / (1.f + __expf(-v));
        }
    }
    __syncthreads();
  }
}

// ---------------------------------------------------------------------------
extern "C" void kernel_launch(void* const* d_in, const int* in_sizes, int n_in,
                              void* d_out, int out_size, void* d_ws, size_t ws_size,
                              hipStream_t stream)
{
  const float* roi   = (const float*)d_in[0];
  const float* bbox  = (const float*)d_in[1];
  const float* dir   = (const float*)d_in[2];
  const float* pri   = (const float*)d_in[3];
  const int*   eidx  = (const int*)d_in[4];
  const float* w1    = (const float*)d_in[5];
  const float* b1    = (const float*)d_in[6];
  const float* g1    = (const float*)d_in[7];
  const float* bb1   = (const float*)d_in[8];
  const float* rm1   = (const float*)d_in[9];
  const float* rv1   = (const float*)d_in[10];
  const float* w2    = (const float*)d_in[11];
  const float* b2    = (const float*)d_in[12];
  const float* g2    = (const float*)d_in[13];
  const float* bb2   = (const float*)d_in[14];
  const float* rm2   = (const float*)d_in[15];
  const float* rv2   = (const float*)d_in[16];
  const float* w3    = (const float*)d_in[17];
  const float* b3    = (const float*)d_in[18];
  const float* niw   = (const float*)d_in[19];
  const float* nib   = (const float*)d_in[20];
  const float* ew1   = (const float*)d_in[21];
  const float* eb1   = (const float*)d_in[22];
  const float* ew2   = (const float*)d_in[23];
  const float* eb2   = (const float*)d_in[24];
  const float* eow   = (const float*)d_in[25];
  const float* eob   = (const float*)d_in[26];

  float* out_node = (float*)d_out;                    // 16384 x 8
  float* out_edge = (float*)d_out + (size_t)M_ * NC_; // 1048576 x 10

  // workspace layout (bytes)
  char* w = (char*)d_ws;
  short*  roiB = (short*)w;                           // 33,554,432
  short*  w1t  = (short*)(w + 33554432);              //  1,048,576
  short*  w2t  = (short*)(w + 34603008);              //    262,144
  short*  w3t  = (short*)(w + 34865152);              //     65,536
  float*  na   = (float*)(w + 34930688);              //    786,432
  short*  h1   = (short*)(w + 35717120);              // 16,777,216

  // fused conversions + node-attr pack (1 launch)
  k_prep<<<8928, 256, 0, stream>>>(roi, (ushort*)roiB, w1, w1t, w2, w2t,
                                   w3, w3t, bbox, dir, pri, na);

  // edge MLP
  k_edge_mfma<<<NE_ / 512, 256, 0, stream>>>(
      na, eidx, ew1, eb1, ew2, eb2, eow, eob, out_edge);

  // node MLP: L1 (m97 GEMM) then fused L2+L3+head
  k_gemm_l1<<<dim3(H1_ / 128, M_ / 128), 256, 0, stream>>>(
      roiB, w1t, b1, g1, bb1, rm1, rv1, h1, M_, F_, H1_);
  k_tail<<<M_ / 32, 256, 0, stream>>>(
      h1, w2t, w3t, b2, g2, bb2, rm2, rv2, b3, niw, nib, out_node);
}

// Round 7
// 249.582 us; speedup vs baseline: 1.1761x; 1.0729x over previous
//
#include <hip/hip_runtime.h>
#include <cstdint>
#include <cstddef>

#define BN_EPSF 1e-5f

constexpr int B_  = 32, N_ = 512, F_ = 1024, E_ = 32768;
constexpr int H1_ = 512, H2_ = 256, H3_ = 128, NC_ = 8, EC_ = 10;
constexpr int M_  = B_ * N_;      // 16384 node rows
constexpr int NE_ = B_ * E_;      // 1048576 edges

typedef short bf16x8 __attribute__((ext_vector_type(8)));
typedef float f32x4  __attribute__((ext_vector_type(4)));

__device__ __forceinline__ short f2bf(float f) {
  union { float f; unsigned u; } v; v.f = f;
  unsigned r = v.u + 0x7fffu + ((v.u >> 16) & 1u);   // RNE
  return (short)(r >> 16);
}
// RNE-round two floats to bf16, pack into u32 (a -> low, b -> high)
__device__ __forceinline__ unsigned rnepack(float a, float b) {
  unsigned ua = __float_as_uint(a); ua = ua + 0x7fffu + ((ua >> 16) & 1u);
  unsigned ub = __float_as_uint(b); ub = ub + 0x7fffu + ((ub >> 16) & 1u);
  return __builtin_amdgcn_perm(ub, ua, 0x07060302u);
}

#define GLDS(gp, lp) __builtin_amdgcn_global_load_lds( \
    (const __attribute__((address_space(1))) void*)(gp), \
    (__attribute__((address_space(3))) void*)(lp), 16, 0, 0)

#define MFMA(a, b, c) __builtin_amdgcn_mfma_f32_16x16x32_bf16((a), (b), (c), 0, 0, 0)

// ---------------------------------------------------------------------------
// prep: roi fp32->bf16 (8192 blocks) | 3x weight transpose+convert (672)
// ---------------------------------------------------------------------------
__device__ __forceinline__ void wt_body(
    const float* __restrict__ W, short* __restrict__ Wt, int K, int N,
    int bx, int by, float (*s)[33])
{
  const int tx = threadIdx.x & 31, ty = threadIdx.x >> 5;
  const int k0 = by * 32, n0 = bx * 32;
#pragma unroll
  for (int r = 0; r < 4; r++)
    s[ty * 4 + r][tx] = W[(size_t)(k0 + ty * 4 + r) * N + n0 + tx];
  __syncthreads();
#pragma unroll
  for (int r = 0; r < 4; r++)
    Wt[(size_t)(n0 + ty * 4 + r) * K + k0 + tx] = f2bf(s[tx][ty * 4 + r]);
}

__global__ __launch_bounds__(256) void k_prep(
    const float* __restrict__ roi, ushort* __restrict__ roiB,
    const float* __restrict__ w1, short* __restrict__ w1t,
    const float* __restrict__ w2, short* __restrict__ w2t,
    const float* __restrict__ w3, short* __restrict__ w3t)
{
  __shared__ float s[32][33];
  const int bx = blockIdx.x;
  if (bx < 8192) {                       // roi -> bf16, 8 elems/thread
    int i = bx * 256 + threadIdx.x;
    float4 a = *(const float4*)(roi + (size_t)i * 8);
    float4 b = *(const float4*)(roi + (size_t)i * 8 + 4);
    unsigned o[4];
    o[0] = rnepack(a.x, a.y); o[1] = rnepack(a.z, a.w);
    o[2] = rnepack(b.x, b.y); o[3] = rnepack(b.z, b.w);
    *(uint4*)(roiB + (size_t)i * 8) = *(uint4*)o;
  } else if (bx < 8704) {                // w1t: K=1024 N=512
    int idx = bx - 8192; wt_body(w1, w1t, F_, H1_, idx & 15, idx >> 4, s);
  } else if (bx < 8832) {                // w2t: K=512 N=256
    int idx = bx - 8704; wt_body(w2, w2t, H1_, H2_, idx & 7, idx >> 3, s);
  } else {                               // w3t: K=256 N=128
    int idx = bx - 8832; wt_body(w3, w3t, H2_, H3_, idx & 3, idx >> 2, s);
  }
}

// ---------------------------------------------------------------------------
// fused edge+L1 kernel. Grid 1536, 2:1 interleave: bx%3<2 -> edge block
// (1024 total, 8 batches x 128 edges, one graph-batch per block), bx%3==2 ->
// L1 GEMM block (512 total, m97 128x128 structure). Edge is latency/VALU-
// bound, L1 is MFMA-bound -> co-resident waves use complementary pipes.
// Arena 49.7 KB -> 3 blocks/CU.
// ---------------------------------------------------------------------------
__global__ __launch_bounds__(256, 3) void k_fused(
    // edge args
    const float* __restrict__ bbox, const float* __restrict__ dir,
    const float* __restrict__ pri, const int* __restrict__ eidx,
    const float* __restrict__ ew1, const float* __restrict__ eb1,
    const float* __restrict__ ew2, const float* __restrict__ eb2,
    const float* __restrict__ eow, const float* __restrict__ eob,
    float* __restrict__ out_edge,
    // L1 args
    const short* __restrict__ roiB, const short* __restrict__ w1t,
    const float* __restrict__ b1, const float* __restrict__ g1,
    const float* __restrict__ bb1, const float* __restrict__ rm1,
    const float* __restrict__ rv1, short* __restrict__ h1)
{
  __shared__ __align__(16) char arena[49728];

  const int bx = blockIdx.x;
  const int rsel = bx % 3;
  const int tid  = threadIdx.x;
  const int wave = tid >> 6, lane = tid & 63;
  const int lm = lane & 15;

  if (rsel == 2) {
    // ================= L1 GEMM block (m97 structure) =================
    const int lb = bx / 3;
    short* As = (short*)arena;            // 128 x 32
    short* Bs = (short*)(arena + 8192);   // 128 x 32
    const int m0 = (lb >> 2) * 128, n0 = (lb & 3) * 128;
    const int wm = wave >> 1, wn = wave & 1;
    const int arow = tid >> 2;
    const int akq  = (tid & 3) * 8;

    f32x4 acc[4][4] = {};
    for (int k0 = 0; k0 < F_; k0 += 32) {
#pragma unroll
      for (int it = 0; it < 2; it++)
        GLDS(roiB + (size_t)(m0 + it * 64 + arow) * F_ + k0 + akq,
             (char*)As + it * 4096 + wave * 1024);
#pragma unroll
      for (int it = 0; it < 2; it++)
        GLDS(w1t + (size_t)(n0 + it * 64 + arow) * F_ + k0 + akq,
             (char*)Bs + it * 4096 + wave * 1024);
      __syncthreads();

      const int ko = (lane >> 4) * 8;
      bf16x8 af[4], bfr[4];
#pragma unroll
      for (int t = 0; t < 4; t++) {
        af[t]  = *(const bf16x8*)&As[(wm * 64 + t * 16 + lm) * 32 + ko];
        bfr[t] = *(const bf16x8*)&Bs[(wn * 64 + t * 16 + lm) * 32 + ko];
      }
#pragma unroll
      for (int ti = 0; ti < 4; ti++)
#pragma unroll
        for (int tj = 0; tj < 4; tj++)
          acc[ti][tj] = MFMA(af[ti], bfr[tj], acc[ti][tj]);
      __syncthreads();
    }
#pragma unroll
    for (int tj = 0; tj < 4; tj++) {
      const int col = n0 + wn * 64 + tj * 16 + lm;
      const float bi = b1[col];
      float s = g1[col] * rsqrtf(rv1[col] + BN_EPSF);
      float t = bb1[col] - rm1[col] * s;
#pragma unroll
      for (int ti = 0; ti < 4; ti++) {
        const int rbase = m0 + wm * 64 + ti * 16 + ((lane >> 4) << 2);
#pragma unroll
        for (int r = 0; r < 4; r++) {
          float v = fmaf(acc[ti][tj][r] + bi, s, t);
          h1[(size_t)(rbase + r) * H1_ + col] = f2bf(fmaxf(v, 0.f));
        }
      }
    }
    return;
  }

  // ================= edge block =================
  const int eb = (bx / 3) * 2 + rsel;     // 0..1023
  const int batch = eb >> 5;              // one batch per block
  const int e_base = eb * 1024;

  short* sA    = (short*)arena;                 // weights stage / X / H2
  short* sH1   = (short*)(arena + 18432);       // 128 x 72
  ushort* sAttr= (ushort*)(arena + 36864);      // 512 x 6 u32 (bf16 attrs)
  float* sB    = (float*)(arena + 49152);       // b1[64] b2[64] bo[16]

  short* sW1 = sA;            // 64 x 32
  short* sW2 = sA + 2048;     // 64 x 64
  short* sW3 = sA + 6144;     // 16 x 64 (rows 10..15 zero)
  short* sX  = sA;            // 128 x 40
  short* sH2 = sA;            // 128 x 72

  const int lk8 = (lane >> 4) * 8;
  const int lr  = (lane >> 4) * 4;

  // ---- stage weights + batch attr table (once per block) ----
  for (int i = tid; i < 2048; i += 256) {
    int n = i >> 5, k = i & 31;
    sW1[i] = (k < 18) ? f2bf(ew1[k * 64 + n]) : (short)0;
  }
  for (int i = tid; i < 4096; i += 256) {
    int n = i >> 6, k = i & 63;
    sW2[i] = f2bf(ew2[k * 64 + n]);
  }
  for (int i = tid; i < 1024; i += 256) {
    int n = i >> 6, k = i & 63;
    sW3[i] = (n < 10) ? f2bf(eow[k * 10 + n]) : (short)0;
  }
  if (tid < 64) { sB[tid] = eb1[tid]; sB[64 + tid] = eb2[tid]; }
  if (tid < 16) sB[128 + tid] = (tid < 10) ? eob[tid] : 0.f;
  {
    const float inv = 1.0f / 1024.0f;
    for (int n = tid; n < 512; n += 256) {
      int gi = batch * 512 + n;
      float4 bv = *(const float4*)(bbox + (size_t)gi * 4);
      float4 dv = *(const float4*)(dir + (size_t)gi * 4);
      float pp = pri[gi];
      unsigned* row = (unsigned*)&sAttr[n * 12];    // 24B stride, 8B aligned
      uint2 a, c, e;
      a.x = rnepack(bv.x * inv, bv.y * inv); a.y = rnepack(bv.z * inv, bv.w * inv);
      c.x = rnepack(dv.x, dv.y);             c.y = rnepack(dv.z, dv.w);
      e.x = rnepack(pp, 0.f);                e.y = 0;
      *(uint2*)(row + 0) = a; *(uint2*)(row + 2) = c; *(uint2*)(row + 4) = e;
    }
  }
  __syncthreads();

  // ---- B-fragments + biases into registers ----
  bf16x8 fW1[4], fW2[4][2], fW3[2];
#pragma unroll
  for (int t = 0; t < 4; t++)
    fW1[t] = *(const bf16x8*)&sW1[(t * 16 + lm) * 32 + lk8];
#pragma unroll
  for (int t = 0; t < 4; t++)
#pragma unroll
    for (int ks = 0; ks < 2; ks++)
      fW2[t][ks] = *(const bf16x8*)&sW2[(t * 16 + lm) * 64 + ks * 32 + lk8];
#pragma unroll
  for (int ks = 0; ks < 2; ks++)
    fW3[ks] = *(const bf16x8*)&sW3[lm * 64 + ks * 32 + lk8];
  float bias1v[4], bias2v[4];
#pragma unroll
  for (int t = 0; t < 4; t++) {
    bias1v[t] = sB[t * 16 + lm];
    bias2v[t] = sB[64 + t * 16 + lm];
  }
  const float biasOv = sB[128 + lm];
  __syncthreads();   // weight-stage region dead; reusable as X

  const int* ei = eidx + (size_t)batch * 2 * E_;

  for (int bi = 0; bi < 8; bi++) {
    const int e0 = e_base + bi * 128;

    // ---- gather 128 edges from LDS attr table -> X rows ----
    if (tid < 128) {
      int kk = (e0 + tid) & (E_ - 1);
      int s = ei[kk], d = ei[E_ + kk];
      const unsigned* ps = (const unsigned*)&sAttr[s * 12];
      const unsigned* pd = (const unsigned*)&sAttr[d * 12];
      uint2 s01 = *(const uint2*)(ps);
      uint2 s23 = *(const uint2*)(ps + 2);
      uint2 s45 = *(const uint2*)(ps + 4);
      uint2 d01 = *(const uint2*)(pd);
      uint2 d23 = *(const uint2*)(pd + 2);
      uint2 d45 = *(const uint2*)(pd + 4);
      unsigned x[16];
      x[0] = s01.x; x[1] = s01.y; x[2] = s23.x; x[3] = s23.y;
      x[4] = (s45.x & 0xffffu) | (d01.x << 16);   // (s8, d0)
      x[5] = (d01.x >> 16) | (d01.y << 16);       // (d1, d2)
      x[6] = (d01.y >> 16) | (d23.x << 16);       // (d3, d4)
      x[7] = (d23.x >> 16) | (d23.y << 16);       // (d5, d6)
      x[8] = (d23.y >> 16) | (d45.x << 16);       // (d7, d8)
#pragma unroll
      for (int i = 9; i < 16; i++) x[i] = 0;
      unsigned* row = (unsigned*)&sX[tid * 40];   // 80B stride, 16B aligned
      *(uint4*)(row + 0)  = *(uint4*)&x[0];
      *(uint4*)(row + 4)  = *(uint4*)&x[4];
      *(uint4*)(row + 8)  = *(uint4*)&x[8];
      *(uint4*)(row + 12) = *(uint4*)&x[12];
    }
    __syncthreads();

    // ---- L1: X(128x32) @ W1 ----
    bf16x8 a1f[2];
#pragma unroll
    for (int ti = 0; ti < 2; ti++)
      a1f[ti] = *(const bf16x8*)&sX[(wave * 32 + ti * 16 + lm) * 40 + lk8];
    f32x4 acc1[2][4] = {};
#pragma unroll
    for (int ti = 0; ti < 2; ti++)
#pragma unroll
      for (int tj = 0; tj < 4; tj++)
        acc1[ti][tj] = MFMA(a1f[ti], fW1[tj], acc1[ti][tj]);
#pragma unroll
    for (int ti = 0; ti < 2; ti++)
#pragma unroll
      for (int tj = 0; tj < 4; tj++)
#pragma unroll
        for (int r = 0; r < 4; r++) {
          int row = wave * 32 + ti * 16 + lr + r;
          float v = acc1[ti][tj][r] + bias1v[tj];
          sH1[row * 72 + tj * 16 + lm] = f2bf(fmaxf(v, 0.f));
        }
    __syncthreads();   // X reads done -> region reusable as H2

    // ---- L2 ----
    bf16x8 a2f[2][2];
#pragma unroll
    for (int ti = 0; ti < 2; ti++)
#pragma unroll
      for (int ks = 0; ks < 2; ks++)
        a2f[ti][ks] = *(const bf16x8*)&sH1[(wave * 32 + ti * 16 + lm) * 72 + ks * 32 + lk8];
    f32x4 acc2[2][4] = {};
#pragma unroll
    for (int ks = 0; ks < 2; ks++)
#pragma unroll
      for (int ti = 0; ti < 2; ti++)
#pragma unroll
        for (int tj = 0; tj < 4; tj++)
          acc2[ti][tj] = MFMA(a2f[ti][ks], fW2[tj][ks], acc2[ti][tj]);
#pragma unroll
    for (int ti = 0; ti < 2; ti++)
#pragma unroll
      for (int tj = 0; tj < 4; tj++)
#pragma unroll
        for (int r = 0; r < 4; r++) {
          int row = wave * 32 + ti * 16 + lr + r;
          float v = acc2[ti][tj][r] + bias2v[tj];
          sH2[row * 72 + tj * 16 + lm] = f2bf(fmaxf(v, 0.f));
        }
    // H2 write->read is within-wave: no barrier

    // ---- L3 + sigmoid ----
    bf16x8 a3f[2][2];
#pragma unroll
    for (int ti = 0; ti < 2; ti++)
#pragma unroll
      for (int ks = 0; ks < 2; ks++)
        a3f[ti][ks] = *(const bf16x8*)&sH2[(wave * 32 + ti * 16 + lm) * 72 + ks * 32 + lk8];
    f32x4 acc3[2] = {};
#pragma unroll
    for (int ks = 0; ks < 2; ks++)
#pragma unroll
      for (int ti = 0; ti < 2; ti++)
        acc3[ti] = MFMA(a3f[ti][ks], fW3[ks], acc3[ti]);
    if (lm < 10) {
#pragma unroll
      for (int ti = 0; ti < 2; ti++)
#pragma unroll
        for (int r = 0; r < 4; r++) {
          int row = wave * 32 + ti * 16 + lr + r;
          float v = acc3[ti][r] + biasOv;
          out_edge[(size_t)(e0 + row) * 10 + lm] = 1.f / (1.f + __expf(-v));
        }
    }
    __syncthreads();   // protect H2/X region before next gather
  }
}

// ---------------------------------------------------------------------------
// fused tail (r5-proven): h2 = relu(bn2(h1@W2)), h3 = relu(h2@W3),
// out = sigmoid(h3@niw + nib). 512 blocks x 32 rows.
// ---------------------------------------------------------------------------
__global__ __launch_bounds__(256) void k_tail(
    const short* __restrict__ h1, const short* __restrict__ w2t,
    const short* __restrict__ w3t,
    const float* __restrict__ b2, const float* __restrict__ g2,
    const float* __restrict__ bb2, const float* __restrict__ rm2,
    const float* __restrict__ rv2,
    const float* __restrict__ b3, const float* __restrict__ niw,
    const float* __restrict__ nib, float* __restrict__ out)
{
  __shared__ __align__(16) char arena[53760];
  short* sA  = (short*)arena;              // [c2][32][32]   4 KB
  short* sB  = (short*)(arena + 4096);     // [c2][256][32] 32 KB
  short* sH2 = (short*)(arena + 36864);    // 32 x 264      16.9 KB
  short* sB3 = (short*)arena;              // [c2][128][32] 16 KB (phase 3)
  short* sH3 = (short*)(arena + 16384);    // 32 x 136       8.7 KB

  const int tid  = threadIdx.x;
  const int wave = tid >> 6, lane = tid & 63;
  const int lm = lane & 15, q = lane >> 4;
  const int wm = wave >> 1, wn = wave & 1;
  const int m0 = blockIdx.x * 32;
  const int srow = tid >> 2;
  const int skq  = (tid & 3) * 8;

  f32x4 acc2[8] = {};
  for (int k0 = 0; k0 < 512; k0 += 64) {
    {
      int c = tid >> 7, row = (tid >> 2) & 31;
      GLDS(h1 + (size_t)(m0 + row) * 512 + k0 + c * 32 + skq,
           (char*)sA + wave * 1024);
    }
#pragma unroll
    for (int it = 0; it < 4; it++)
#pragma unroll
      for (int c = 0; c < 2; c++)
        GLDS(w2t + (size_t)(it * 64 + srow) * 512 + k0 + c * 32 + skq,
             (char*)sB + c * 16384 + it * 4096 + wave * 1024);
    __syncthreads();
#pragma unroll
    for (int c = 0; c < 2; c++) {
      bf16x8 af = *(const bf16x8*)&sA[c * 1024 + (wm * 16 + lm) * 32 + q * 8];
#pragma unroll
      for (int nt = 0; nt < 8; nt++) {
        bf16x8 bfr = *(const bf16x8*)&sB[c * 8192 + (wn * 128 + nt * 16 + lm) * 32 + q * 8];
        acc2[nt] = MFMA(af, bfr, acc2[nt]);
      }
    }
    __syncthreads();
  }
#pragma unroll
  for (int nt = 0; nt < 8; nt++) {
    int col = wn * 128 + nt * 16 + lm;
    float s = g2[col] * rsqrtf(rv2[col] + BN_EPSF);
    float t = bb2[col] - rm2[col] * s;
    float bi = b2[col];
#pragma unroll
    for (int r = 0; r < 4; r++) {
      float v = fmaf(acc2[nt][r] + bi, s, t);
      sH2[(wm * 16 + q * 4 + r) * 264 + col] = f2bf(fmaxf(v, 0.f));
    }
  }
  __syncthreads();

  f32x4 acc3[4] = {};
  for (int k0 = 0; k0 < 256; k0 += 64) {
#pragma unroll
    for (int it = 0; it < 2; it++)
#pragma unroll
      for (int c = 0; c < 2; c++)
        GLDS(w3t + (size_t)(it * 64 + srow) * 256 + k0 + c * 32 + skq,
             (char*)sB3 + c * 8192 + it * 4096 + wave * 1024);
    __syncthreads();
#pragma unroll
    for (int c = 0; c < 2; c++) {
      bf16x8 af = *(const bf16x8*)&sH2[(wm * 16 + lm) * 264 + k0 + c * 32 + q * 8];
#pragma unroll
      for (int nt = 0; nt < 4; nt++) {
        bf16x8 bfr = *(const bf16x8*)&sB3[c * 4096 + (wn * 64 + nt * 16 + lm) * 32 + q * 8];
        acc3[nt] = MFMA(af, bfr, acc3[nt]);
      }
    }
    __syncthreads();
  }
#pragma unroll
  for (int nt = 0; nt < 4; nt++) {
    int col = wn * 64 + nt * 16 + lm;
    float bi = b3[col];
#pragma unroll
    for (int r = 0; r < 4; r++) {
      float v = acc3[nt][r] + bi;
      sH3[(wm * 16 + q * 4 + r) * 136 + col] = f2bf(fmaxf(v, 0.f));
    }
  }
  __syncthreads();

  if (wave < 2) {
    f32x4 a4 = {};
#pragma unroll
    for (int c = 0; c < 4; c++) {
      ushort tmp[8];
#pragma unroll
      for (int j = 0; j < 8; j++) {
        int k = c * 32 + q * 8 + j;
        tmp[j] = (lm < 8) ? (ushort)f2bf(niw[k * 8 + lm]) : (ushort)0;
      }
      bf16x8 fw = *(bf16x8*)tmp;
      bf16x8 af4 = *(const bf16x8*)&sH3[(wave * 16 + lm) * 136 + c * 32 + q * 8];
      a4 = MFMA(af4, fw, a4);
    }
    if (lm < 8) {
      float bi = nib[lm];
#pragma unroll
      for (int r = 0; r < 4; r++) {
        float v = a4[r] + bi;
        out[(size_t)(m0 + wave * 16 + q * 4 + r) * 8 + lm] = 1.f / (1.f + __expf(-v));
      }
    }
  }
}

// ---------------------------------------------------------------------------
extern "C" void kernel_launch(void* const* d_in, const int* in_sizes, int n_in,
                              void* d_out, int out_size, void* d_ws, size_t ws_size,
                              hipStream_t stream)
{
  const float* roi   = (const float*)d_in[0];
  const float* bbox  = (const float*)d_in[1];
  const float* dir   = (const float*)d_in[2];
  const float* pri   = (const float*)d_in[3];
  const int*   eidx  = (const int*)d_in[4];
  const float* w1    = (const float*)d_in[5];
  const float* b1    = (const float*)d_in[6];
  const float* g1    = (const float*)d_in[7];
  const float* bb1   = (const float*)d_in[8];
  const float* rm1   = (const float*)d_in[9];
  const float* rv1   = (const float*)d_in[10];
  const float* w2    = (const float*)d_in[11];
  const float* b2    = (const float*)d_in[12];
  const float* g2    = (const float*)d_in[13];
  const float* bb2   = (const float*)d_in[14];
  const float* rm2   = (const float*)d_in[15];
  const float* rv2   = (const float*)d_in[16];
  const float* w3    = (const float*)d_in[17];
  const float* b3    = (const float*)d_in[18];
  const float* niw   = (const float*)d_in[19];
  const float* nib   = (const float*)d_in[20];
  const float* ew1   = (const float*)d_in[21];
  const float* eb1   = (const float*)d_in[22];
  const float* ew2   = (const float*)d_in[23];
  const float* eb2   = (const float*)d_in[24];
  const float* eow   = (const float*)d_in[25];
  const float* eob   = (const float*)d_in[26];

  float* out_node = (float*)d_out;                    // 16384 x 8
  float* out_edge = (float*)d_out + (size_t)M_ * NC_; // 1048576 x 10

  // workspace layout (bytes)
  char* w = (char*)d_ws;
  short*  roiB = (short*)w;                           // 33,554,432
  short*  w1t  = (short*)(w + 33554432);              //  1,048,576
  short*  w2t  = (short*)(w + 34603008);              //    262,144
  short*  w3t  = (short*)(w + 34865152);              //     65,536
  short*  h1   = (short*)(w + 35717120);              // 16,777,216

  // launch 1: conversions (roi bf16 + weight transposes)
  k_prep<<<8864, 256, 0, stream>>>(roi, (ushort*)roiB, w1, w1t, w2, w2t,
                                   w3, w3t);

  // launch 2: fused edge MLP + node L1 GEMM (independent, 2:1 interleave)
  k_fused<<<1536, 256, 0, stream>>>(
      bbox, dir, pri, eidx, ew1, eb1, ew2, eb2, eow, eob, out_edge,
      roiB, w1t, b1, g1, bb1, rm1, rv1, h1);

  // launch 3: fused L2+L3+head
  k_tail<<<M_ / 32, 256, 0, stream>>>(
      h1, w2t, w3t, b2, g2, bb2, rm2, rv2, b3, niw, nib, out_node);
}